// Round 30
// baseline (100.105 us; speedup 1.0000x reference)
//
#include <hip/hip_runtime.h>
#include <math.h>

#define B_    16
#define CIN   64
#define COUT  128
#define H_    128
#define W_    128
#define CI2   128            // 2*CIN (x ++ silu(x))
#define KTOT  1152           // 9 taps * CI2

typedef __bf16 bf16x8 __attribute__((ext_vector_type(8)));
typedef float  f32x16 __attribute__((ext_vector_type(16)));

#define XT_BYTES  ((size_t)B_ * H_ * W_ * CIN * 2)   // 33,554,432 (x only)
#define WC_BYTES  ((size_t)COUT * KTOT * 2)          // 294,912
#define Z_OFF     (XT_BYTES + WC_BYTES)
#define WS_NEED   (Z_OFF + 4096)

// ---------- merged prep: xt (4096 blocks) + weights (576 blocks) ----------
// xt: x (NCHW fp32) -> Xt (NHWC bf16, x only, 64 ci/pos)
// wc: 32x32-frag chunk-major order: chunk c = kk*9+tap (16KB);
//     frag-row fr = m*4+kstep (1KB); lane = hi*32 + (co&31); elem e.
//     A lane mapping (32x32x16): row = lane&31, k = (lane>>5)*8 + e.
__global__ __launch_bounds__(256) void prep_all(const float* __restrict__ x,
                                                const float* __restrict__ sw,
                                                const float* __restrict__ bw,
                                                __bf16* __restrict__ xt,
                                                __bf16* __restrict__ wc,
                                                float* __restrict__ zp) {
    const int bid = blockIdx.x;
    const int t   = threadIdx.x;
    if (bid < 4096) {
        __shared__ __align__(16) __bf16 tile[64][72];
        const int w0 = (bid & 1) * 64;
        const int h  = (bid >> 1) & 127;
        const int b  = bid >> 8;
        const float* xb = x + ((size_t)(b * CIN) * H_ + h) * W_ + w0;
#pragma unroll
        for (int rep = 0; rep < 16; ++rep) {
            const int idx = rep * 256 + t;
            const int ci = idx >> 6, w = idx & 63;
            tile[w][ci] = (__bf16)xb[(size_t)ci * H_ * W_ + w];
        }
        __syncthreads();
        __bf16* ob = xt + (((size_t)b * H_ + h) * W_ + w0) * CIN;
#pragma unroll
        for (int rep = 0; rep < 2; ++rep) {
            const int idx = rep * 256 + t;
            const int w = idx >> 3, sl = idx & 7;
            *(bf16x8*)(ob + (size_t)w * CIN + sl * 8) =
                *(const bf16x8*)(&tile[w][sl * 8]);
        }
    } else {
        const int i = (bid - 4096) * 256 + t;
        if (bid == 4096) zp[t] = 0.f;            // zeros page (1 KiB)
        if (i >= COUT * KTOT) return;
        const int co = i / KTOT, k = i - co * KTOT;
        const int tap = k >> 7, ci2 = k & 127;
        float v;
        if (ci2 < CIN) {
            const float* p = sw + ((size_t)(co * CIN + ci2) * 9 + tap) * 4;
            v = p[0] + p[1] + p[2] + p[3];
        } else {
            v = bw[(size_t)(co * CIN + (ci2 - CIN)) * 9 + tap];
        }
        const int m = co >> 5, row31 = co & 31;
        const int kk = ci2 >> 6, cl = ci2 & 63;
        const int kstep = cl >> 4, hi = (cl >> 3) & 1, e = cl & 7;
        const int c = kk * 9 + tap;
        const size_t off =
            ((size_t)((c * 16 + m * 4 + kstep)) * 64 + hi * 32 + row31) * 8 + e;
        wc[off] = (__bf16)v;
    }
}

// ---------- main: wide-tile K-split conv on 32x32x16 MFMA ----------
// block: 128 couts x (8h x 32w = 256 pos); 4 waves, each 128co x (2h x 32w).
// per phase (K=64): 4 ksteps x {4 af + 2 bf reads, 8 mfma_32x32x16}.
// LDS: bh 43520B + A chunk dbuf 2x16384B = 76288B -> 2 blocks/CU.
// bh staged once (bf16 x); in-LDS silu at kk boundary; chunk-10 prestage.
__global__ __launch_bounds__(256, 2) void kan_mfma(const __bf16* __restrict__ xt,
                                                   const __bf16* __restrict__ wc,
                                                   const float* __restrict__ zp,
                                                   float* __restrict__ out) {
    __shared__ __align__(16) char bh[2720 * 16];     // 340 cells * 128B
    __shared__ __align__(16) char asA[1024 * 16];    // A chunk buf A: 16 KB
    __shared__ __align__(16) char asB[1024 * 16];    // A chunk buf B: 16 KB
    const int t    = threadIdx.x;
    const int lane = t & 63, wn = t >> 6;            // wave wn: h rows wn*2..+1
    const int l31 = lane & 31, lh = lane >> 5;

    // XCD-chunked bijective swizzle (1024 % 8 == 0)
    const int orig = blockIdx.x;
    const int wid  = (orig & 7) * 128 + (orig >> 3);
    const int b  = wid >> 6;
    const int hy = (wid >> 2) & 15, wx = wid & 3;
    const int w0 = wx * 32, h0 = hy * 8;

    const size_t xbase = (size_t)b * (H_ * W_ * CIN);

    // ---- stage B halo (bf16 x, 64 ci/cell): 2720 16B slots; swizzle q^(cell&7)
#define STAGEB_()                                                               \
    _Pragma("unroll")                                                           \
    for (int i = 0; i < 11; ++i) {                                              \
        const int s = i * 256 + t;                                              \
        if (s < 2720) {                                                         \
            const int cell = s >> 3, q = s & 7;                                 \
            const int ih = cell / 34, iw = cell - ih * 34;                      \
            const int gh = h0 + ih - 1, gw = w0 + iw - 1;                       \
            const int chunk = q ^ (cell & 7);                                   \
            const void* src;                                                    \
            if (gh >= 0 && gh < H_ && gw >= 0 && gw < W_)                       \
                src = (const void*)(xt + xbase +                                \
                      ((size_t)(gh * W_ + gw)) * CIN + chunk * 8);              \
            else                                                                \
                src = (const void*)zp;                                          \
            __builtin_amdgcn_global_load_lds(                                   \
                (const __attribute__((address_space(1))) unsigned int*)src,     \
                (__attribute__((address_space(3))) unsigned int*)(bh + s * 16), \
                16, 0, 0);                                                      \
        }                                                                       \
    }

    // ---- stage one 16KB A chunk (1024 x 16B, linear both sides)
#define STAGEC_(buf, c)                                                         \
    _Pragma("unroll")                                                           \
    for (int i = 0; i < 4; ++i) {                                               \
        const int s = i * 256 + t;                                              \
        __builtin_amdgcn_global_load_lds(                                       \
            (const __attribute__((address_space(1))) unsigned int*)              \
                (wc + (size_t)(c) * 8192 + s * 8),                              \
            (__attribute__((address_space(3))) unsigned int*)((buf) + s * 16),  \
            16, 0, 0);                                                          \
    }

    // ---- one phase: 4 ksteps of {4 af + 2 bf reads, 8 mfma_32x32x16}
    // A frag-row fr = m*4+kstep at (buf + fr*1024 + lane*16)
    // B: cell = (wn*2 + n + kh)*34 + l31 + kw; slot = kstep*2 + lh (swizzled)
#define COMPUTE_(buf, tp)                                                       \
    {                                                                           \
        const int kh_ = ((tp) * 11) >> 5;                                       \
        const int kw_ = (tp) - kh_ * 3;                                         \
        _Pragma("unroll")                                                       \
        for (int ks = 0; ks < 4; ++ks) {                                        \
            bf16x8 af[4], bf[2];                                                \
            _Pragma("unroll")                                                   \
            for (int m = 0; m < 4; ++m)                                         \
                af[m] = *(const bf16x8*)((buf) + (m * 4 + ks) * 1024 +          \
                                         lane * 16);                            \
            _Pragma("unroll")                                                   \
            for (int n = 0; n < 2; ++n) {                                       \
                const int cell = (wn * 2 + n + kh_) * 34 + l31 + kw_;           \
                const int swz  = (ks * 2 + lh) ^ (cell & 7);                    \
                bf[n] = *(const bf16x8*)(bh + cell * 128 + swz * 16);           \
            }                                                                   \
            __builtin_amdgcn_s_setprio(1);                                      \
            _Pragma("unroll")                                                   \
            for (int m = 0; m < 4; ++m)                                         \
                _Pragma("unroll")                                               \
                for (int n = 0; n < 2; ++n)                                     \
                    acc[m][n] = __builtin_amdgcn_mfma_f32_32x32x16_bf16(        \
                        af[m], bf[n], acc[m][n], 0, 0, 0);                      \
            __builtin_amdgcn_s_setprio(0);                                      \
        }                                                                       \
    }

    f32x16 acc[4][2] = {};

    STAGEB_();
    STAGEC_(asA, 0);
    __syncthreads();                 // bh(x) + A chunk 0 ready

    // ---- K-half 0: taps 0..8, chunks 0..8 (stage 1..9 ahead)
#pragma unroll 1
    for (int tap = 0; tap < 9; ++tap) {
        const int c = tap;
        STAGEC_((c & 1) ? asA : asB, c + 1);   // chunks 1..9 (9 lands in asB)
        COMPUTE_((c & 1) ? asB : asA, tap);
        __syncthreads();
    }

    // ---- kk boundary: prestage chunk 10 (asA free), then bh := silu(bh)
    STAGEC_(asA, 10);
#pragma unroll
    for (int i = 0; i < 11; ++i) {
        const int s = i * 256 + t;
        if (s < 2720) {
            bf16x8 v = *(const bf16x8*)(bh + s * 16);
#pragma unroll
            for (int e = 0; e < 8; ++e) {
                const float f = (float)v[e];
                v[e] = (__bf16)(f / (1.f + __expf(-f)));
            }
            *(bf16x8*)(bh + s * 16) = v;
        }
    }
    __syncthreads();                 // silu'd halo + chunk 10 ready

    // ---- K-half 1: taps 0..8, chunks 9..17 (9 in asB, 10 in asA)
#pragma unroll 1
    for (int tap = 0; tap < 9; ++tap) {
        const int c = 9 + tap;
        if (c >= 10 && c < 17) STAGEC_((c & 1) ? asA : asB, c + 1);
        COMPUTE_((c & 1) ? asB : asA, tap);
        __syncthreads();
    }

    // ---- epilogue (32x32 D map): co = m*32 + (r&3)+8*(r>>2)+4*lh;
    //      oh = h0 + wn*2 + n; ow = w0 + l31  -> full 128B store lines
    float* ob = out + (size_t)b * COUT * H_ * W_;
#pragma unroll
    for (int m = 0; m < 4; ++m) {
#pragma unroll
        for (int n = 0; n < 2; ++n) {
            const int oh = h0 + wn * 2 + n;
            const int ow = w0 + l31;
#pragma unroll
            for (int r = 0; r < 16; ++r) {
                const int co = m * 32 + (r & 3) + 8 * (r >> 2) + 4 * lh;
                ob[((size_t)co * H_ + oh) * W_ + ow] = acc[m][n][r];
            }
        }
    }
#undef STAGEB_
#undef STAGEC_
#undef COMPUTE_
}

// ---------- fallback (round-0 fp32 path, used only if ws too small) ----------
#define TS   16
#define COB  8
#define TIN  18
__global__ __launch_bounds__(256) void spline_sum_kernel(const float* __restrict__ sw,
                                                         float* __restrict__ wsum) {
    int i = blockIdx.x * 256 + threadIdx.x;
    if (i < COUT * CIN * 9) {
        const float4 v = *reinterpret_cast<const float4*>(sw + (size_t)i * 4);
        wsum[i] = v.x + v.y + v.z + v.w;
    }
}
__global__ __launch_bounds__(256) void kan_conv(const float* __restrict__ x,
                                                const float* __restrict__ wsp,
                                                const float* __restrict__ wb,
                                                float* __restrict__ out) {
    __shared__ float xsm[TIN][20];
    __shared__ float ssm[TIN][20];
    const int t = threadIdx.x, tx = t & 15, ty = t >> 4;
    const int w0 = (blockIdx.x & 7) * TS, h0 = (blockIdx.x >> 3) * TS;
    const int co0 = blockIdx.y * COB, b = blockIdx.z;
    float acc[COB];
#pragma unroll
    for (int i = 0; i < COB; ++i) acc[i] = 0.f;
    const float* xb = x + (size_t)b * CIN * H_ * W_;
    for (int ci = 0; ci < CIN; ++ci) {
        __syncthreads();
        const float* xc = xb + (size_t)ci * H_ * W_;
        for (int p = t; p < TIN * TIN; p += 256) {
            int r = p / TIN, c = p - r * TIN;
            int ih = h0 + r - 1, iw = w0 + c - 1;
            float v = 0.f;
            if (ih >= 0 && ih < H_ && iw >= 0 && iw < W_) v = xc[ih * W_ + iw];
            xsm[r][c] = v;
            ssm[r][c] = v / (1.f + expf(-v));
        }
        __syncthreads();
        float xv[9], sv[9];
#pragma unroll
        for (int kh = 0; kh < 3; ++kh)
#pragma unroll
            for (int kw = 0; kw < 3; ++kw) {
                xv[kh * 3 + kw] = xsm[ty + kh][tx + kw];
                sv[kh * 3 + kw] = ssm[ty + kh][tx + kw];
            }
#pragma unroll
        for (int co = 0; co < COB; ++co) {
            const float* w1 = wsp + ((size_t)(co0 + co) * CIN + ci) * 9;
            const float* w2 = wb  + ((size_t)(co0 + co) * CIN + ci) * 9;
#pragma unroll
            for (int k = 0; k < 9; ++k)
                acc[co] += xv[k] * w1[k] + sv[k] * w2[k];
        }
    }
    const int oh = h0 + ty, ow = w0 + tx;
#pragma unroll
    for (int co = 0; co < COB; ++co)
        out[(((size_t)b * COUT + (co0 + co)) * H_ + oh) * W_ + ow] = acc[co];
}

extern "C" void kernel_launch(void* const* d_in, const int* in_sizes, int n_in,
                              void* d_out, int out_size, void* d_ws, size_t ws_size,
                              hipStream_t stream) {
    const float* x  = (const float*)d_in[0];
    const float* sw = (const float*)d_in[1];   // (COUT,CIN,3,3,4)
    const float* bw = (const float*)d_in[2];   // (COUT,CIN,3,3)
    float* out = (float*)d_out;

    if (ws_size >= WS_NEED) {
        __bf16* xt  = (__bf16*)d_ws;
        __bf16* wcp = (__bf16*)((char*)d_ws + XT_BYTES);
        float*  zp  = (float*)((char*)d_ws + Z_OFF);
        prep_all<<<dim3(4096 + 576), 256, 0, stream>>>(x, sw, bw, xt, wcp, zp);
        kan_mfma<<<dim3(1024), 256, 0, stream>>>(xt, wcp, zp, out);
    } else {
        float* wsum = (float*)d_ws;
        spline_sum_kernel<<<(COUT * CIN * 9 + 255) / 256, 256, 0, stream>>>(sw, wsum);
        kan_conv<<<dim3(64, COUT / COB, B_), 256, 0, stream>>>(x, wsum, bw, out);
    }
}

// Round 31
// 94.302 us; speedup vs baseline: 1.0615x; 1.0615x over previous
//
#include <hip/hip_runtime.h>
#include <math.h>

#define B_    16
#define CIN   64
#define COUT  128
#define H_    128
#define W_    128
#define CI2   128            // 2*CIN (x ++ silu(x))
#define KTOT  1152           // 9 taps * CI2

typedef __bf16 bf16x8 __attribute__((ext_vector_type(8)));
typedef float  f32x4  __attribute__((ext_vector_type(4)));

#define XT_BYTES  ((size_t)B_ * H_ * W_ * CIN * 2)   // 33,554,432 (x only)
#define WC_BYTES  ((size_t)COUT * KTOT * 2)          // 294,912
#define Z_OFF     (XT_BYTES + WC_BYTES)
#define WS_NEED   (Z_OFF + 4096)

// ---------- merged prep: xt (4096 blocks) + weights (576 blocks) ----------
// xt: x (NCHW fp32) -> Xt (NHWC bf16, x only, 64 ci/pos)
// wc: CHUNK-major fragment order (r24-verified): chunk c = kk*9+tap;
//     elem off = ((c*16 + f*2 + j)*64 + lq*16 + l15)*8 + e.
__global__ __launch_bounds__(256) void prep_all(const float* __restrict__ x,
                                                const float* __restrict__ sw,
                                                const float* __restrict__ bw,
                                                __bf16* __restrict__ xt,
                                                __bf16* __restrict__ wc,
                                                float* __restrict__ zp) {
    const int bid = blockIdx.x;
    const int t   = threadIdx.x;
    if (bid < 4096) {
        // ---- xt transpose block
        __shared__ __align__(16) __bf16 tile[64][72];
        const int w0 = (bid & 1) * 64;
        const int h  = (bid >> 1) & 127;
        const int b  = bid >> 8;
        const float* xb = x + ((size_t)(b * CIN) * H_ + h) * W_ + w0;
#pragma unroll
        for (int rep = 0; rep < 16; ++rep) {
            const int idx = rep * 256 + t;
            const int ci = idx >> 6, w = idx & 63;
            tile[w][ci] = (__bf16)xb[(size_t)ci * H_ * W_ + w];
        }
        __syncthreads();
        __bf16* ob = xt + (((size_t)b * H_ + h) * W_ + w0) * CIN;
#pragma unroll
        for (int rep = 0; rep < 2; ++rep) {
            const int idx = rep * 256 + t;
            const int w = idx >> 3, sl = idx & 7;
            *(bf16x8*)(ob + (size_t)w * CIN + sl * 8) =
                *(const bf16x8*)(&tile[w][sl * 8]);
        }
    } else {
        // ---- weight permute block
        const int i = (bid - 4096) * 256 + t;
        if (bid == 4096) zp[t] = 0.f;            // zeros page (1 KiB)
        if (i >= COUT * KTOT) return;
        const int co = i / KTOT, k = i - co * KTOT;
        const int tap = k >> 7, ci2 = k & 127;
        float v;
        if (ci2 < CIN) {
            const float* p = sw + ((size_t)(co * CIN + ci2) * 9 + tap) * 4;
            v = p[0] + p[1] + p[2] + p[3];
        } else {
            v = bw[(size_t)(co * CIN + (ci2 - CIN)) * 9 + tap];
        }
        const int f = co >> 4, l15 = co & 15;
        const int kk = ci2 >> 6, j = (ci2 >> 5) & 1;
        const int lq = (ci2 >> 3) & 3, e = ci2 & 7;
        const int c = kk * 9 + tap;
        const size_t off =
            ((size_t)(c * 16 + f * 2 + j)) * 512 + (lq * 16 + l15) * 8 + e;
        wc[off] = (__bf16)v;
    }
}

// ---------- main: wide-tile K-split MFMA conv, in-LDS silu for K-half 1 ----------
// block: 128 couts x (8h x 32w = 256 pos); 4 waves, each 128co x 64pos.
// LDS: bh 43520B + A chunk dbuf 2x16384B = 76288B -> 2 blocks/CU.
// bh staged once (bf16 x halo); at kk boundary transformed IN PLACE to silu(x).
// A-chunk 10 prestaged during the silu pass (hides its latency).
__global__ __launch_bounds__(256, 2) void kan_mfma(const __bf16* __restrict__ xt,
                                                   const __bf16* __restrict__ wc,
                                                   const float* __restrict__ zp,
                                                   float* __restrict__ out) {
    __shared__ __align__(16) char bh[2720 * 16];     // 340 cells * 128B
    __shared__ __align__(16) char asA[1024 * 16];    // A chunk buf A: 16 KB
    __shared__ __align__(16) char asB[1024 * 16];    // A chunk buf B: 16 KB
    const int t    = threadIdx.x;
    const int lane = t & 63, wn = t >> 6;            // 4 waves = 4 n-quadrants
    const int l15 = lane & 15, lq = lane >> 4;

    // XCD-chunked bijective swizzle (1024 % 8 == 0)
    const int orig = blockIdx.x;
    const int wid  = (orig & 7) * 128 + (orig >> 3);
    const int b  = wid >> 6;
    const int hy = (wid >> 2) & 15, wx = wid & 3;
    const int w0 = wx * 32, h0 = hy * 8;

    const size_t xbase = (size_t)b * (H_ * W_ * CIN);

    // ---- stage B halo (bf16 x, 64 ci/cell): 2720 16B slots; swizzle q^(cell&7)
#define STAGEB_()                                                               \
    _Pragma("unroll")                                                           \
    for (int i = 0; i < 11; ++i) {                                              \
        const int s = i * 256 + t;                                              \
        if (s < 2720) {                                                         \
            const int cell = s >> 3, q = s & 7;                                 \
            const int ih = cell / 34, iw = cell - ih * 34;                      \
            const int gh = h0 + ih - 1, gw = w0 + iw - 1;                       \
            const int chunk = q ^ (cell & 7);                                   \
            const void* src;                                                    \
            if (gh >= 0 && gh < H_ && gw >= 0 && gw < W_)                       \
                src = (const void*)(xt + xbase +                                \
                      ((size_t)(gh * W_ + gw)) * CIN + chunk * 8);              \
            else                                                                \
                src = (const void*)zp;                                          \
            __builtin_amdgcn_global_load_lds(                                   \
                (const __attribute__((address_space(1))) unsigned int*)src,     \
                (__attribute__((address_space(3))) unsigned int*)(bh + s * 16), \
                16, 0, 0);                                                      \
        }                                                                       \
    }

    // ---- stage one 16KB A chunk (1024 x 16B, linear both sides)
#define STAGEC_(buf, c)                                                         \
    _Pragma("unroll")                                                           \
    for (int i = 0; i < 4; ++i) {                                               \
        const int s = i * 256 + t;                                              \
        __builtin_amdgcn_global_load_lds(                                       \
            (const __attribute__((address_space(1))) unsigned int*)              \
                (wc + (size_t)(c) * 8192 + s * 8),                              \
            (__attribute__((address_space(3))) unsigned int*)((buf) + s * 16),  \
            16, 0, 0);                                                          \
    }

    // ---- one phase: 2 j-groups of {8 af + 4 bf reads, 32 MFMA}
#define COMPUTE_(buf, tp)                                                       \
    {                                                                           \
        const int kh_ = ((tp) * 11) >> 5;                                       \
        const int kw_ = (tp) - kh_ * 3;                                         \
        _Pragma("unroll")                                                       \
        for (int j = 0; j < 2; ++j) {                                           \
            bf16x8 af[8], bf[4];                                                \
            _Pragma("unroll")                                                   \
            for (int m = 0; m < 8; ++m)                                         \
                af[m] = *(const bf16x8*)((buf) + (m * 2 + j) * 1024 +           \
                                         lane * 16);                            \
            _Pragma("unroll")                                                   \
            for (int n = 0; n < 4; ++n) {                                       \
                const int cell = (wn * 2 + (n >> 1) + kh_) * 34 +               \
                                 (n & 1) * 16 + l15 + kw_;                      \
                const int swz  = (j * 4 + lq) ^ (cell & 7);                     \
                bf[n] = *(const bf16x8*)(bh + cell * 128 + swz * 16);           \
            }                                                                   \
            __builtin_amdgcn_s_setprio(1);                                      \
            _Pragma("unroll")                                                   \
            for (int m = 0; m < 8; ++m)                                         \
                _Pragma("unroll")                                               \
                for (int n = 0; n < 4; ++n)                                     \
                    acc[m][n] = __builtin_amdgcn_mfma_f32_16x16x32_bf16(        \
                        af[m], bf[n], acc[m][n], 0, 0, 0);                      \
            __builtin_amdgcn_s_setprio(0);                                      \
        }                                                                       \
    }

    f32x4 acc[8][4] = {};

    STAGEB_();
    STAGEC_(asA, 0);
    __syncthreads();                 // bh(x) + A chunk 0 ready

    // ---- K-half 0: taps 0..8, chunks 0..8 (stage 1..9 ahead)
#pragma unroll 1
    for (int tap = 0; tap < 9; ++tap) {
        const int c = tap;
        STAGEC_((c & 1) ? asA : asB, c + 1);   // chunks 1..9 (9 lands in asB)
        COMPUTE_((c & 1) ? asB : asA, tap);
        __syncthreads();
    }

    // ---- kk boundary: prestage chunk 10 (asA is free), then bh := silu(bh)
    STAGEC_(asA, 10);                // latency hides under the silu pass
#pragma unroll
    for (int i = 0; i < 11; ++i) {
        const int s = i * 256 + t;
        if (s < 2720) {
            bf16x8 v = *(const bf16x8*)(bh + s * 16);
#pragma unroll
            for (int e = 0; e < 8; ++e) {
                const float f = (float)v[e];
                v[e] = (__bf16)(f / (1.f + __expf(-f)));
            }
            *(bf16x8*)(bh + s * 16) = v;
        }
    }
    __syncthreads();                 // silu'd halo + chunk 10 ready

    // ---- K-half 1: taps 0..8, chunks 9..17 (9 in asB, 10 in asA; stage 11..17)
#pragma unroll 1
    for (int tap = 0; tap < 9; ++tap) {
        const int c = 9 + tap;
        if (c >= 10 && c < 17) STAGEC_((c & 1) ? asA : asB, c + 1);
        COMPUTE_((c & 1) ? asB : asA, tap);
        __syncthreads();
    }

    // ---- epilogue: co = m*16 + lq*4 + r; oh = h0+wn*2+(n>>1); ow = w0+(n&1)*16+l15
    float* ob = out + (size_t)b * COUT * H_ * W_;
#pragma unroll
    for (int m = 0; m < 8; ++m) {
        const int co = m * 16 + lq * 4;
#pragma unroll
        for (int n = 0; n < 4; ++n) {
            const int oh = h0 + wn * 2 + (n >> 1);
            const int ow = w0 + (n & 1) * 16 + l15;
            float* p = ob + ((size_t)co * H_ + oh) * W_ + ow;
#pragma unroll
            for (int r = 0; r < 4; ++r)
                p[(size_t)r * H_ * W_] = acc[m][n][r];
        }
    }
#undef STAGEB_
#undef STAGEC_
#undef COMPUTE_
}

// ---------- fallback (round-0 fp32 path, used only if ws too small) ----------
#define TS   16
#define COB  8
#define TIN  18
__global__ __launch_bounds__(256) void spline_sum_kernel(const float* __restrict__ sw,
                                                         float* __restrict__ wsum) {
    int i = blockIdx.x * 256 + threadIdx.x;
    if (i < COUT * CIN * 9) {
        const float4 v = *reinterpret_cast<const float4*>(sw + (size_t)i * 4);
        wsum[i] = v.x + v.y + v.z + v.w;
    }
}
__global__ __launch_bounds__(256) void kan_conv(const float* __restrict__ x,
                                                const float* __restrict__ wsp,
                                                const float* __restrict__ wb,
                                                float* __restrict__ out) {
    __shared__ float xsm[TIN][20];
    __shared__ float ssm[TIN][20];
    const int t = threadIdx.x, tx = t & 15, ty = t >> 4;
    const int w0 = (blockIdx.x & 7) * TS, h0 = (blockIdx.x >> 3) * TS;
    const int co0 = blockIdx.y * COB, b = blockIdx.z;
    float acc[COB];
#pragma unroll
    for (int i = 0; i < COB; ++i) acc[i] = 0.f;
    const float* xb = x + (size_t)b * CIN * H_ * W_;
    for (int ci = 0; ci < CIN; ++ci) {
        __syncthreads();
        const float* xc = xb + (size_t)ci * H_ * W_;
        for (int p = t; p < TIN * TIN; p += 256) {
            int r = p / TIN, c = p - r * TIN;
            int ih = h0 + r - 1, iw = w0 + c - 1;
            float v = 0.f;
            if (ih >= 0 && ih < H_ && iw >= 0 && iw < W_) v = xc[ih * W_ + iw];
            xsm[r][c] = v;
            ssm[r][c] = v / (1.f + expf(-v));
        }
        __syncthreads();
        float xv[9], sv[9];
#pragma unroll
        for (int kh = 0; kh < 3; ++kh)
#pragma unroll
            for (int kw = 0; kw < 3; ++kw) {
                xv[kh * 3 + kw] = xsm[ty + kh][tx + kw];
                sv[kh * 3 + kw] = ssm[ty + kh][tx + kw];
            }
#pragma unroll
        for (int co = 0; co < COB; ++co) {
            const float* w1 = wsp + ((size_t)(co0 + co) * CIN + ci) * 9;
            const float* w2 = wb  + ((size_t)(co0 + co) * CIN + ci) * 9;
#pragma unroll
            for (int k = 0; k < 9; ++k)
                acc[co] += xv[k] * w1[k] + sv[k] * w2[k];
        }
    }
    const int oh = h0 + ty, ow = w0 + tx;
#pragma unroll
    for (int co = 0; co < COB; ++co)
        out[(((size_t)b * COUT + (co0 + co)) * H_ + oh) * W_ + ow] = acc[co];
}

extern "C" void kernel_launch(void* const* d_in, const int* in_sizes, int n_in,
                              void* d_out, int out_size, void* d_ws, size_t ws_size,
                              hipStream_t stream) {
    const float* x  = (const float*)d_in[0];
    const float* sw = (const float*)d_in[1];   // (COUT,CIN,3,3,4)
    const float* bw = (const float*)d_in[2];   // (COUT,CIN,3,3)
    float* out = (float*)d_out;

    if (ws_size >= WS_NEED) {
        __bf16* xt  = (__bf16*)d_ws;
        __bf16* wcp = (__bf16*)((char*)d_ws + XT_BYTES);
        float*  zp  = (float*)((char*)d_ws + Z_OFF);
        prep_all<<<dim3(4096 + 576), 256, 0, stream>>>(x, sw, bw, xt, wcp, zp);
        kan_mfma<<<dim3(1024), 256, 0, stream>>>(xt, wcp, zp, out);
    } else {
        float* wsum = (float*)d_ws;
        spline_sum_kernel<<<(COUT * CIN * 9 + 255) / 256, 256, 0, stream>>>(sw, wsum);
        kan_conv<<<dim3(64, COUT / COB, B_), 256, 0, stream>>>(x, wsum, bw, out);
    }
}